// Round 4
// baseline (2350.645 us; speedup 1.0000x reference)
//
#include <hip/hip_runtime.h>
#include <hip/hip_bf16.h>

// N=100000 nodes, 64 in-feats, 32 hidden, E=3200000 edges per type.
// Pipeline: count (int atomics) -> dinv -> bucket offsets (scan) ->
// xw (bf16-packed xws, pre-scaled by dinv[src]) -> pass1 (direct radix bin,
// 4B packed entry/edge) -> pass2 (per-(bucket,type) LDS scatter, bf16 gather,
// unroll-8 ILP) -> epilogue.
// Round-3 lesson: pass2 was latency-bound (782 blocks, 2-deep ILP, 128B/edge
// gather). Fix: 3126 blocks, 8-deep ILP, 64B/edge bf16 gather.

#define RS 64                  // dsts per bucket
#define RBITS 6
#define SCAN_BLOCK 1024

__device__ __forceinline__ unsigned bf16_rn(float f) {
    unsigned u = __float_as_uint(f);
    return (u + 0x7FFFu + ((u >> 16) & 1u)) >> 16;
}
__device__ __forceinline__ float bf_lo(unsigned w) { return __uint_as_float(w << 16); }
__device__ __forceinline__ float bf_hi(unsigned w) { return __uint_as_float(w & 0xFFFF0000u); }

// --- node in-degree counts (int atomics) ---
__global__ void count_kernel(const int* __restrict__ ei_n, const int* __restrict__ ei_s,
                             int* __restrict__ cnt, int N, int En, int Es) {
    int gid = blockIdx.x * blockDim.x + threadIdx.x;
    if (gid < En) {
        atomicAdd(&cnt[ei_n[En + gid]], 1);
    } else if (gid < En + Es) {
        int e = gid - En;
        atomicAdd(&cnt[N + ei_s[Es + e]], 1);
    }
}

__global__ void dinv_kernel(const int* __restrict__ cnt, float* __restrict__ dinv, int M) {
    int i = blockIdx.x * blockDim.x + threadIdx.x;
    if (i < M) dinv[i] = rsqrtf((float)cnt[i] + 1.0f);   // +1 self-loop
}

// --- per-bucket counts from node counts ---
__global__ void bucket_sum_kernel(const int* __restrict__ cnt,
                                  int* __restrict__ bcnt, int* __restrict__ bscan,
                                  int N, int NBKr, int M2) {
    int b = blockIdx.x * blockDim.x + threadIdx.x;
    if (b >= M2) return;
    int type = (b >= NBKr) ? 1 : 0;
    int lo = (b - type * NBKr) * RS;
    int hi = min(lo + RS, N);
    const int* c = cnt + (size_t)type * N;
    int s = 0;
    for (int i = lo; i < hi; ++i) s += c[i];
    bcnt[b] = s;
    bscan[b] = s;
}

// --- hierarchical inclusive scan over bscan[0..M2) ---
__global__ void scan1_kernel(int* __restrict__ arr, int* __restrict__ bsum, int M) {
    __shared__ int s[SCAN_BLOCK];
    int i = blockIdx.x * SCAN_BLOCK + threadIdx.x;
    s[threadIdx.x] = (i < M) ? arr[i] : 0;
    __syncthreads();
#pragma unroll
    for (int off = 1; off < SCAN_BLOCK; off <<= 1) {
        int t = (threadIdx.x >= off) ? s[threadIdx.x - off] : 0;
        __syncthreads();
        s[threadIdx.x] += t;
        __syncthreads();
    }
    if (i < M) arr[i] = s[threadIdx.x];
    if (threadIdx.x == SCAN_BLOCK - 1) bsum[blockIdx.x] = s[SCAN_BLOCK - 1];
}

__global__ void scan2_kernel(int* __restrict__ bsum, int nb) {
    __shared__ int s[SCAN_BLOCK];
    s[threadIdx.x] = (threadIdx.x < nb) ? bsum[threadIdx.x] : 0;
    __syncthreads();
#pragma unroll
    for (int off = 1; off < SCAN_BLOCK; off <<= 1) {
        int t = (threadIdx.x >= off) ? s[threadIdx.x - off] : 0;
        __syncthreads();
        s[threadIdx.x] += t;
        __syncthreads();
    }
    if (threadIdx.x < nb) bsum[threadIdx.x] = s[threadIdx.x];
}

__global__ void scan3_kernel(int* __restrict__ arr, const int* __restrict__ bsum, int M) {
    int i = blockIdx.x * SCAN_BLOCK + threadIdx.x;
    if (blockIdx.x > 0 && i < M) arr[i] += bsum[blockIdx.x - 1];
}

__global__ void cursor_init_kernel(const int* __restrict__ bscan, const int* __restrict__ bcnt,
                                   int* __restrict__ cursor, int M2) {
    int i = blockIdx.x * blockDim.x + threadIdx.x;
    if (i < M2) cursor[i] = bscan[i] - bcnt[i];
}

// --- xws = (x @ W) * dinv[node], packed bf16x2 (feats 2sl, 2sl+1 per word) ---
__global__ void xw_kernel(const float* __restrict__ x,
                          const float* __restrict__ Wn, const float* __restrict__ Ws,
                          const float* __restrict__ dinv,
                          unsigned* __restrict__ xws_u, int N) {
    __shared__ float wn[64 * 32];
    __shared__ float wsm[64 * 32];
    for (int i = threadIdx.x; i < 64 * 32; i += blockDim.x) {
        wn[i] = Wn[i];
        wsm[i] = Ws[i];
    }
    __syncthreads();
    int lane = threadIdx.x & 31;
    int node = blockIdx.x * (blockDim.x >> 5) + (threadIdx.x >> 5);
    if (node >= N) return;

    const float4* x4 = (const float4*)(x + (size_t)node * 64);
    float an = 0.f, as = 0.f;
#pragma unroll
    for (int k4 = 0; k4 < 16; ++k4) {
        float4 xv = x4[k4];
        int k = k4 * 4;
        an += xv.x * wn[(k + 0) * 32 + lane] + xv.y * wn[(k + 1) * 32 + lane]
            + xv.z * wn[(k + 2) * 32 + lane] + xv.w * wn[(k + 3) * 32 + lane];
        as += xv.x * wsm[(k + 0) * 32 + lane] + xv.y * wsm[(k + 1) * 32 + lane]
            + xv.z * wsm[(k + 2) * 32 + lane] + xv.w * wsm[(k + 3) * 32 + lane];
    }
    float vn = an * dinv[node];
    float vs = as * dinv[N + node];
    int sl = lane & 15;
    float vn0 = __shfl(vn, 2 * sl, 32);
    float vn1 = __shfl(vn, 2 * sl + 1, 32);
    float vs0 = __shfl(vs, 2 * sl, 32);
    float vs1 = __shfl(vs, 2 * sl + 1, 32);
    if (lane < 16) {
        xws_u[(size_t)node * 16 + sl]         = bf16_rn(vn0) | (bf16_rn(vn1) << 16);
        xws_u[((size_t)N + node) * 16 + sl]   = bf16_rn(vs0) | (bf16_rn(vs1) << 16);
    }
}

// --- Pass 1: direct radix bin. packed = (dstLocal<<20) | src ---
__global__ void pass1_kernel(const int* __restrict__ ei_n, const int* __restrict__ ei_s,
                             int* __restrict__ cursor, unsigned int* __restrict__ packed,
                             int En, int Es, int NBKr) {
    int gid = blockIdx.x * blockDim.x + threadIdx.x;
    int src, dst, bin;
    if (gid < En) {
        src = ei_n[gid]; dst = ei_n[En + gid]; bin = dst >> RBITS;
    } else if (gid < En + Es) {
        int e = gid - En;
        src = ei_s[e]; dst = ei_s[Es + e]; bin = NBKr + (dst >> RBITS);
    } else {
        return;
    }
    int pos = atomicAdd(&cursor[bin], 1);
    packed[pos] = ((unsigned)(dst & (RS - 1)) << 20) | (unsigned)src;
}

// --- Pass 2: per-(bucket,type) LDS scatter-accumulate, bf16 gather, unroll-8 ---
__global__ void __launch_bounds__(512, 4)
pass2_kernel(const unsigned int* __restrict__ packed,
             const int* __restrict__ bcnt, const int* __restrict__ bscan,
             const unsigned* __restrict__ xws_u, unsigned* __restrict__ acc_u,
             int N, int NBKr) {
    __shared__ float acc[RS * 33];                 // +1 word pad per row: bank-spread
    int b = blockIdx.x;
    int tid = threadIdx.x;
    for (int i = tid; i < RS * 33; i += 512) acc[i] = 0.f;
    __syncthreads();
    int type = (b >= NBKr) ? 1 : 0;
    int slot = tid >> 4;                           // 32 slots of 16 lanes
    int sl = tid & 15;
    int e1 = bscan[b];
    int s1 = e1 - bcnt[b];
    const unsigned* xb = xws_u + (size_t)type * N * 16;

    int j = s1 + slot;
    for (; j + 224 < e1; j += 256) {
        unsigned p[8], w[8];
#pragma unroll
        for (int k = 0; k < 8; ++k) p[k] = packed[j + 32 * k];
#pragma unroll
        for (int k = 0; k < 8; ++k) w[k] = xb[(size_t)(p[k] & 0xFFFFFu) * 16 + sl];
#pragma unroll
        for (int k = 0; k < 8; ++k) {
            unsigned dl = p[k] >> 20;
            atomicAdd(&acc[dl * 33 + 2 * sl], bf_lo(w[k]));
            atomicAdd(&acc[dl * 33 + 2 * sl + 1], bf_hi(w[k]));
        }
    }
    for (; j < e1; j += 32) {
        unsigned p0 = packed[j];
        unsigned w0 = xb[(size_t)(p0 & 0xFFFFFu) * 16 + sl];
        unsigned dl = p0 >> 20;
        atomicAdd(&acc[dl * 33 + 2 * sl], bf_lo(w0));
        atomicAdd(&acc[dl * 33 + 2 * sl + 1], bf_hi(w0));
    }
    __syncthreads();
    // flush tile as packed bf16
    int nbase = (b - type * NBKr) * RS;
    for (int idx = tid; idx < RS * 16; idx += 512) {
        int dl = idx >> 4, ss = idx & 15;
        int d = nbase + dl;
        if (d < N) {
            float f0 = acc[dl * 33 + 2 * ss];
            float f1 = acc[dl * 33 + 2 * ss + 1];
            acc_u[((size_t)type * N + d) * 16 + ss] = bf16_rn(f0) | (bf16_rn(f1) << 16);
        }
    }
}

// --- Epilogue: 16 lanes per node ---
__global__ void epilogue_kernel(const unsigned* __restrict__ acc_u,
                                const unsigned* __restrict__ xws_u,
                                const float* __restrict__ dinv,
                                const float* __restrict__ b_n, const float* __restrict__ b_s,
                                const float* __restrict__ W_lin, const float* __restrict__ b_lin,
                                float* __restrict__ out, int N) {
    int gid = blockIdx.x * blockDim.x + threadIdx.x;
    int node = gid >> 4, sl = gid & 15;
    if (node >= N) return;
    unsigned an = acc_u[(size_t)node * 16 + sl];
    unsigned av = acc_u[((size_t)N + node) * 16 + sl];
    unsigned xn = xws_u[(size_t)node * 16 + sl];
    unsigned xs = xws_u[((size_t)N + node) * 16 + sl];
    float dn = dinv[node], dsv = dinv[N + node];
    float h0 = (bf_lo(an) + bf_lo(xn)) * dn + b_n[2 * sl]
             + (bf_lo(av) + bf_lo(xs)) * dsv + b_s[2 * sl];
    float h1 = (bf_hi(an) + bf_hi(xn)) * dn + b_n[2 * sl + 1]
             + (bf_hi(av) + bf_hi(xs)) * dsv + b_s[2 * sl + 1];
    float p = fmaxf(h0, 0.f) * W_lin[2 * sl] + fmaxf(h1, 0.f) * W_lin[2 * sl + 1];
#pragma unroll
    for (int off = 8; off > 0; off >>= 1) p += __shfl_xor(p, off, 16);
    if (sl == 0) out[node] = p + b_lin[0];
}

extern "C" void kernel_launch(void* const* d_in, const int* in_sizes, int n_in,
                              void* d_out, int out_size, void* d_ws, size_t ws_size,
                              hipStream_t stream) {
    const float* x     = (const float*)d_in[0];
    const int*   ei_n  = (const int*)d_in[1];
    const int*   ei_s  = (const int*)d_in[2];
    const float* W_n   = (const float*)d_in[3];
    const float* b_n   = (const float*)d_in[4];
    const float* W_s   = (const float*)d_in[5];
    const float* b_s   = (const float*)d_in[6];
    const float* W_lin = (const float*)d_in[7];
    const float* b_lin = (const float*)d_in[8];
    float* out = (float*)d_out;

    const int N    = in_sizes[0] / 64;   // 100000
    const int En   = in_sizes[1] / 2;    // 3200000
    const int Es   = in_sizes[2] / 2;    // 3200000
    const int Etot = En + Es;
    const int M    = 2 * N;
    const int NBKr = (N + RS - 1) / RS;  // 1563
    const int M2   = 2 * NBKr;           // 3126

    // Workspace (4B words), ~52.8 MB:
    // cnt[2N] | dinv[2N] | bcnt[M2] | bscan[M2] | cursor[M2] | bsum[1024]
    // | xws_u[32N words] | acc_u[32N words] | packed[Etot]
    int*   cnt    = (int*)d_ws;
    float* dinv   = (float*)(cnt + (size_t)M);
    int*   bcnt   = (int*)(dinv + (size_t)M);
    int*   bscan  = bcnt + M2;
    int*   cursor = bscan + M2;
    int*   bsum   = cursor + M2;
    unsigned* xws_u = (unsigned*)(bsum + 1024);
    unsigned* acc_u = xws_u + (size_t)16 * M;
    unsigned* packed = acc_u + (size_t)16 * M;

    hipMemsetAsync(cnt, 0, (size_t)M * sizeof(int), stream);

    count_kernel<<<(Etot + 255) / 256, 256, 0, stream>>>(ei_n, ei_s, cnt, N, En, Es);
    dinv_kernel<<<(M + 255) / 256, 256, 0, stream>>>(cnt, dinv, M);
    bucket_sum_kernel<<<(M2 + 255) / 256, 256, 0, stream>>>(cnt, bcnt, bscan, N, NBKr, M2);

    int nb = (M2 + SCAN_BLOCK - 1) / SCAN_BLOCK;  // 4
    scan1_kernel<<<nb, SCAN_BLOCK, 0, stream>>>(bscan, bsum, M2);
    scan2_kernel<<<1, SCAN_BLOCK, 0, stream>>>(bsum, nb);
    scan3_kernel<<<nb, SCAN_BLOCK, 0, stream>>>(bscan, bsum, M2);
    cursor_init_kernel<<<(M2 + 255) / 256, 256, 0, stream>>>(bscan, bcnt, cursor, M2);

    xw_kernel<<<(N + 7) / 8, 256, 0, stream>>>(x, W_n, W_s, dinv, xws_u, N);

    pass1_kernel<<<(Etot + 255) / 256, 256, 0, stream>>>(ei_n, ei_s, cursor, packed, En, Es, NBKr);

    pass2_kernel<<<M2, 512, 0, stream>>>(packed, bcnt, bscan, xws_u, acc_u, N, NBKr);

    epilogue_kernel<<<(int)(((size_t)N * 16 + 255) / 256), 256, 0, stream>>>(
        acc_u, xws_u, dinv, b_n, b_s, W_lin, b_lin, out, N);
}

// Round 5
// 727.643 us; speedup vs baseline: 3.2305x; 3.2305x over previous
//
#include <hip/hip_runtime.h>
#include <hip/hip_fp16.h>

// N=100000 nodes, 64 in-feats, 32 hidden, E=3200000 edges per type.
// Strategy: round-1's flat push-scatter (proven at the global-atomic rate
// ceiling, 309 G ops/s) with the atomic count HALVED via packed-f16 atomics
// (global_atomic_pk_add_f16): 204.8M f32 atomics -> 102.4M pk ops.
// Rounds 2-4 showed every sort/bin/LDS-aggregation scheme costs more than
// the atomics they save (bin write-amplification 595us, LDS f32 atomics
// ~same rate as global: 1100us).
// Numerics: msgs quantized to f16 (2^-11 rel), ~33-term f16 accumulation,
// final dinv[dst] (~0.17x) shrinks accumulated error; predicted absmax ~2e-3
// vs 1.6e-2 threshold.

__global__ void count_kernel(const int* __restrict__ ei_n, const int* __restrict__ ei_s,
                             int* __restrict__ cnt, int N, int En, int Es) {
    int gid = blockIdx.x * blockDim.x + threadIdx.x;
    if (gid < En) {
        atomicAdd(&cnt[ei_n[En + gid]], 1);
    } else if (gid < En + Es) {
        int e = gid - En;
        atomicAdd(&cnt[N + ei_s[Es + e]], 1);
    }
}

__global__ void dinv_kernel(const int* __restrict__ cnt, float* __restrict__ dinv, int M) {
    int i = blockIdx.x * blockDim.x + threadIdx.x;
    if (i < M) dinv[i] = rsqrtf((float)cnt[i] + 1.0f);   // +1 = self-loop
}

// xws[type][node] = (x[node] @ W_type) * dinv[type][node], packed __half2
// (feats 2sl, 2sl+1 in word sl, sl<16). Also seeds acc with the same value
// (self-loop message), so no acc memset and no self-add in the epilogue.
__global__ void xw_kernel(const float* __restrict__ x,
                          const float* __restrict__ Wn, const float* __restrict__ Ws,
                          const float* __restrict__ dinv,
                          __half2* __restrict__ xws, __half2* __restrict__ acc, int N) {
    __shared__ float wn[64 * 32];
    __shared__ float wsm[64 * 32];
    for (int i = threadIdx.x; i < 64 * 32; i += blockDim.x) {
        wn[i] = Wn[i];
        wsm[i] = Ws[i];
    }
    __syncthreads();
    int lane = threadIdx.x & 31;
    int node = blockIdx.x * (blockDim.x >> 5) + (threadIdx.x >> 5);
    if (node >= N) return;

    const float4* x4 = (const float4*)(x + (size_t)node * 64);
    float an = 0.f, as = 0.f;
#pragma unroll
    for (int k4 = 0; k4 < 16; ++k4) {
        float4 xv = x4[k4];
        int k = k4 * 4;
        an += xv.x * wn[(k + 0) * 32 + lane] + xv.y * wn[(k + 1) * 32 + lane]
            + xv.z * wn[(k + 2) * 32 + lane] + xv.w * wn[(k + 3) * 32 + lane];
        as += xv.x * wsm[(k + 0) * 32 + lane] + xv.y * wsm[(k + 1) * 32 + lane]
            + xv.z * wsm[(k + 2) * 32 + lane] + xv.w * wsm[(k + 3) * 32 + lane];
    }
    float vn = an * dinv[node];
    float vs = as * dinv[N + node];
    int sl = lane & 15;
    float vn0 = __shfl(vn, 2 * sl, 32);
    float vn1 = __shfl(vn, 2 * sl + 1, 32);
    float vs0 = __shfl(vs, 2 * sl, 32);
    float vs1 = __shfl(vs, 2 * sl + 1, 32);
    if (lane < 16) {
        __half2 hn = __floats2half2_rn(vn0, vn1);
        __half2 hs = __floats2half2_rn(vs0, vs1);
        size_t on = (size_t)node * 16 + sl;
        size_t os = ((size_t)N + node) * 16 + sl;
        xws[on] = hn;
        acc[on] = hn;
        xws[os] = hs;
        acc[os] = hs;
    }
}

// Per edge: 16 lanes gather packed msg row (64B) and pk_add_f16 into acc[dst].
__global__ void scatter_kernel(const int* __restrict__ ei_n, const int* __restrict__ ei_s,
                               const __half2* __restrict__ xws, __half2* __restrict__ acc,
                               int N, int En, int Es) {
    unsigned int gid = blockIdx.x * blockDim.x + threadIdx.x;
    unsigned int e = gid >> 4;
    int sl = gid & 15;
    int src, dst;
    size_t base;
    if (e < (unsigned)En) {
        src = ei_n[e]; dst = ei_n[En + e]; base = 0;
    } else if (e < (unsigned)(En + Es)) {
        unsigned e2 = e - En;
        src = ei_s[e2]; dst = ei_s[Es + e2]; base = (size_t)N;
    } else {
        return;
    }
    __half2 w = xws[(base + src) * 16 + sl];
    unsafeAtomicAdd(&acc[(base + dst) * 16 + sl], w);   // global_atomic_pk_add_f16
}

// out[d] = dot(relu(acc_n*dinv_n + b_n + acc_s*dinv_s + b_s), W_lin) + b_lin
__global__ void epilogue_kernel(const __half2* __restrict__ acc,
                                const float* __restrict__ dinv,
                                const float* __restrict__ b_n, const float* __restrict__ b_s,
                                const float* __restrict__ W_lin, const float* __restrict__ b_lin,
                                float* __restrict__ out, int N) {
    int gid = blockIdx.x * blockDim.x + threadIdx.x;
    int node = gid >> 4, sl = gid & 15;
    if (node >= N) return;
    float2 an = __half22float2(acc[(size_t)node * 16 + sl]);
    float2 as = __half22float2(acc[((size_t)N + node) * 16 + sl]);
    float dn = dinv[node], dsv = dinv[N + node];
    float h0 = an.x * dn + b_n[2 * sl] + as.x * dsv + b_s[2 * sl];
    float h1 = an.y * dn + b_n[2 * sl + 1] + as.y * dsv + b_s[2 * sl + 1];
    float p = fmaxf(h0, 0.f) * W_lin[2 * sl] + fmaxf(h1, 0.f) * W_lin[2 * sl + 1];
#pragma unroll
    for (int off = 8; off > 0; off >>= 1) p += __shfl_xor(p, off, 16);
    if (sl == 0) out[node] = p + b_lin[0];
}

extern "C" void kernel_launch(void* const* d_in, const int* in_sizes, int n_in,
                              void* d_out, int out_size, void* d_ws, size_t ws_size,
                              hipStream_t stream) {
    const float* x     = (const float*)d_in[0];
    const int*   ei_n  = (const int*)d_in[1];
    const int*   ei_s  = (const int*)d_in[2];
    const float* W_n   = (const float*)d_in[3];
    const float* b_n   = (const float*)d_in[4];
    const float* W_s   = (const float*)d_in[5];
    const float* b_s   = (const float*)d_in[6];
    const float* W_lin = (const float*)d_in[7];
    const float* b_lin = (const float*)d_in[8];
    float* out = (float*)d_out;

    const int N    = in_sizes[0] / 64;   // 100000
    const int En   = in_sizes[1] / 2;    // 3200000
    const int Es   = in_sizes[2] / 2;    // 3200000
    const int Etot = En + Es;
    const int M    = 2 * N;

    // Workspace (4B words), ~27 MB:
    // cnt[2N] | dinv[2N] | xws[2N*16 half2] | acc[2N*16 half2]
    int*     cnt  = (int*)d_ws;
    float*   dinv = (float*)(cnt + (size_t)M);
    __half2* xws  = (__half2*)(dinv + (size_t)M);
    __half2* acc  = xws + (size_t)16 * M;

    hipMemsetAsync(cnt, 0, (size_t)M * sizeof(int), stream);

    count_kernel<<<(Etot + 255) / 256, 256, 0, stream>>>(ei_n, ei_s, cnt, N, En, Es);
    dinv_kernel<<<(M + 255) / 256, 256, 0, stream>>>(cnt, dinv, M);

    xw_kernel<<<(N + 7) / 8, 256, 0, stream>>>(x, W_n, W_s, dinv, xws, acc, N);

    {
        size_t total = (size_t)Etot * 16;
        int blocks = (int)((total + 255) / 256);
        scatter_kernel<<<blocks, 256, 0, stream>>>(ei_n, ei_s, xws, acc, N, En, Es);
    }

    epilogue_kernel<<<(int)(((size_t)N * 16 + 255) / 256), 256, 0, stream>>>(
        acc, dinv, b_n, b_s, W_lin, b_lin, out, N);
}